// Round 12
// baseline (527.716 us; speedup 1.0000x reference)
//
#include <hip/hip_runtime.h>
#include <hip/hip_bf16.h>
#include <stdint.h>

typedef unsigned short ushort_t;
typedef __attribute__((ext_vector_type(8))) short short8;
typedef __attribute__((ext_vector_type(4))) float floatx4;

__device__ __forceinline__ ushort_t f2b(float f) {
    unsigned u = __float_as_uint(f);
    unsigned r = (u + 0x7FFFu + ((u >> 16) & 1u)) >> 16;
    return (ushort_t)r;
}
__device__ __forceinline__ float b2f(ushort_t h) {
    return __uint_as_float(((unsigned)h) << 16);
}
__device__ __forceinline__ float elu1(float f) {
    return (f > 0.f) ? (f + 1.f) : __expf(f);
}

#define GLDS16(srcp, dstp)                                                          \
    __builtin_amdgcn_global_load_lds(                                               \
        (const __attribute__((address_space(1))) unsigned int*)(srcp),              \
        (__attribute__((address_space(3))) unsigned int*)(dstp), 16, 0, 0)

// ---------------- fused prep: wqT transpose | wpT transpose | x->bf16 | zero ----------------
__global__ __launch_bounds__(256) void prep_kernel(
    const float* __restrict__ x, const float* __restrict__ wq, const float* __restrict__ wp,
    ushort_t* __restrict__ xb, ushort_t* __restrict__ wqT, ushort_t* __restrict__ wpT,
    float* __restrict__ kvz)
{
    __shared__ float tile[32][33];
    const int bid = blockIdx.x;
    const int t = threadIdx.x;
    const int tx = t & 31, ty = t >> 5;

    if (bid < 3072) {
        // wqT[c][r] = bf16(wq[r][c]); R=1024, C=3072
        const int c0 = (bid % 96) * 32, r0 = (bid / 96) * 32;
#pragma unroll
        for (int k = 0; k < 4; ++k) {
            int a = ty * 4 + k;
            tile[a][tx] = wq[(size_t)(r0 + a) * 3072 + c0 + tx];
        }
        __syncthreads();
#pragma unroll
        for (int k = 0; k < 4; ++k) {
            int a = ty * 4 + k;
            wqT[(size_t)(c0 + a) * 1024 + r0 + tx] = f2b(tile[tx][a]);
        }
    } else if (bid < 4096) {
        const int b2 = bid - 3072;
        const int c0 = (b2 & 31) * 32, r0 = (b2 >> 5) * 32;
#pragma unroll
        for (int k = 0; k < 4; ++k) {
            int a = ty * 4 + k;
            tile[a][tx] = wp[(size_t)(r0 + a) * 1024 + c0 + tx];
        }
        __syncthreads();
#pragma unroll
        for (int k = 0; k < 4; ++k) {
            int a = ty * 4 + k;
            wpT[(size_t)(c0 + a) * 1024 + r0 + tx] = f2b(tile[tx][a]);
        }
    } else if (bid < 5120) {
        // x -> bf16, 8 elems/thread/iter; n8 = 33554432/8
        for (int i = (bid - 4096) * 256 + t; i < 4194304; i += 1024 * 256) {
            const float4 f0 = *(const float4*)&x[(size_t)i * 8];
            const float4 f1 = *(const float4*)&x[(size_t)i * 8 + 4];
            ushort4 o0, o1;
            o0.x = f2b(f0.x); o0.y = f2b(f0.y); o0.z = f2b(f0.z); o0.w = f2b(f0.w);
            o1.x = f2b(f1.x); o1.y = f2b(f1.y); o1.z = f2b(f1.z); o1.w = f2b(f1.w);
            *(ushort4*)&xb[(size_t)i * 8]     = o0;
            *(ushort4*)&xb[(size_t)i * 8 + 4] = o1;
        }
    } else {
        for (int i = (bid - 5120) * 256 + t; i < 266240; i += 128 * 256) kvz[i] = 0.f;
    }
}

// ---------------- persistent 256x256 8-phase GEMM (16x16x32): C = A @ Bt^T, K=1024 ----------------
// L2-blocked XCD tile mapping:
//   MODE 0 (qkv, 128 rows x 12 cols): XCD x -> colgroup (x&1)*6, rowband (x>>1)*32.
//     round ot: 32 blocks cover ~5.3 rows x 6 cols -> B colgroup (3MB) L2-resident.
//   MODE 1 (proj, 128 rows x 4 cols): XCD x -> rowband x*16, all 4 cols.
// MODE 0 epilogue: bias + elu+1 on q,k; packed 8B scatter to [3][bh][8192][64]
// MODE 1 epilogue: bias; fp32 linear [M][Nt]
template<int MODE>
__global__ __launch_bounds__(512, 2) void gemm256(
    const ushort_t* __restrict__ A, const ushort_t* __restrict__ Bt,
    const float* __restrict__ bias,
    ushort_t* __restrict__ out_u16, float* __restrict__ out_f32,
    int Nt, int nt)
{
    extern __shared__ ushort_t lds[];   // 65536 elements = 128 KiB
    constexpr int KK = 1024;

    const int tid  = threadIdx.x;
    const int wave = tid >> 6;
    const int lane = tid & 63;
    const int wm_i = wave >> 2;
    const int wn_i = wave & 3;
    const int fr   = lane & 15;
    const int fq   = lane >> 4;

    const int bid  = (int)blockIdx.x;

    const int trow = tid >> 3;
    const int csw  = ((tid & 7) ^ (trow & 7)) << 3;
    const int tcolB = ((tid >> 8) << 6) + (trow & 31);

    const int dstA = wave * 512;
    const int dstB = 16384 + wave * 512;

    const int sw0 = (fq ^ (fr & 7)) << 3;
    const int sw1 = sw0 ^ 32;
    const int abase = (wm_i * 64 + fr) * 64;
    const int bbase = (wn_i * 32 + fr) * 64;
    int loA0[2][2], loA1[2][2], loB0[2][2], loB1[2][2];
#pragma unroll
    for (int bf = 0; bf < 2; ++bf)
#pragma unroll
        for (int q = 0; q < 2; ++q) {
            loA0[bf][q] = bf * 32768 + q * 8192 + abase + sw0;
            loA1[bf][q] = bf * 32768 + q * 8192 + abase + sw1;
            loB0[bf][q] = bf * 32768 + 16384 + q * 8192 + bbase + sw0;
            loB1[bf][q] = bf * 32768 + 16384 + q * 8192 + bbase + sw1;
        }

    floatx4 acc[8][4];
    const floatx4 z4 = {0.f, 0.f, 0.f, 0.f};
#pragma unroll
    for (int i = 0; i < 8; ++i)
#pragma unroll
        for (int j = 0; j < 4; ++j) acc[i][j] = z4;

    short8 a[4][2], b[2][2];

    // L2-blocked tile mapping
    auto tile_of = [&](int ot) -> int {
        const int x = bid & 7, lid = bid >> 3;
        const int tl = ot * 32 + lid;
        if (MODE == 0) {
            const int row = ((x >> 1) << 5) + tl / 6;
            const int col = (x & 1) * 6 + (tl % 6);
            return row * 12 + col;
        } else {
            const int row = (x << 4) + (tl >> 2);
            const int col = tl & 3;
            return row * 4 + col;
        }
    };

    auto tilebase = [&](int t, const ushort_t*& sA, const ushort_t*& sB, int& mm, int& nn) {
        const int nbx = (MODE == 0) ? 12 : 4;
        const int byy = t / nbx;
        const int bxx = t - byy * nbx;
        mm = byy << 8; nn = bxx << 8;
        sA = A  + (size_t)(mm + trow)  * KK + csw;
        sB = Bt + (size_t)(nn + tcolB) * KK + csw;
    };

    auto stageA = [&](const ushort_t* sp, int buf, int h, int ko) {
        ushort_t* d = lds + buf * 32768 + h * 8192 + dstA;
        GLDS16(sp + h * (64 * KK) + ko, d);
        GLDS16(sp + h * (64 * KK) + 128 * KK + ko, d + 4096);
    };
    auto stageB = [&](const ushort_t* sp, int buf, int h, int ko) {
        ushort_t* d = lds + buf * 32768 + h * 8192 + dstB;
        GLDS16(sp + h * (32 * KK) + ko, d);
        GLDS16(sp + h * (32 * KK) + 128 * KK + ko, d + 4096);
    };
    auto loadA = [&](int buf, int qr) {
        const int o0 = loA0[buf][qr], o1 = loA1[buf][qr];
#pragma unroll
        for (int i = 0; i < 4; ++i) {
            a[i][0] = *(const short8*)(lds + o0 + i * 1024);
            a[i][1] = *(const short8*)(lds + o1 + i * 1024);
        }
    };
    auto loadB = [&](int buf, int qc) {
        const int o0 = loB0[buf][qc], o1 = loB1[buf][qc];
#pragma unroll
        for (int j = 0; j < 2; ++j) {
            b[j][0] = *(const short8*)(lds + o0 + j * 1024);
            b[j][1] = *(const short8*)(lds + o1 + j * 1024);
        }
    };
    // swapped operands: D^T -> lane fq*4+r indexes n (cols), fr indexes m (rows)
    auto mma = [&](int qr, int qc) {
#pragma unroll
        for (int i = 0; i < 4; ++i)
#pragma unroll
            for (int j = 0; j < 2; ++j) {
                acc[qr * 4 + i][qc * 2 + j] =
                    __builtin_amdgcn_mfma_f32_16x16x32_bf16(b[j][0], a[i][0], acc[qr * 4 + i][qc * 2 + j], 0, 0, 0);
                acc[qr * 4 + i][qc * 2 + j] =
                    __builtin_amdgcn_mfma_f32_16x16x32_bf16(b[j][1], a[i][1], acc[qr * 4 + i][qc * 2 + j], 0, 0, 0);
            }
    };

    auto epilogue = [&](int m0, int n0) {
        float4 bv[4];
#pragma unroll
        for (int cj = 0; cj < 4; ++cj) {
            const int nb = n0 + wn_i * 64 + (cj >> 1) * 32 + (cj & 1) * 16 + fq * 4;
            bv[cj] = *(const float4*)&bias[nb];
        }
#pragma unroll
        for (int ri = 0; ri < 8; ++ri) {
            const int m = m0 + wm_i * 128 + (ri >> 2) * 64 + (ri & 3) * 16 + fr;
#pragma unroll
            for (int cj = 0; cj < 4; ++cj) {
                const int col = n0 + wn_i * 64 + (cj >> 1) * 32 + (cj & 1) * 16 + fq * 4;
                float v0 = acc[ri][cj][0] + bv[cj].x;
                float v1 = acc[ri][cj][1] + bv[cj].y;
                float v2 = acc[ri][cj][2] + bv[cj].z;
                float v3 = acc[ri][cj][3] + bv[cj].w;
                if (MODE == 0) {
                    const int s  = col >> 10;
                    const int c  = col & 1023;
                    const int h  = c >> 6;
                    const int d  = c & 63;
                    const int bb = m >> 13;
                    const int n  = m & 8191;
                    if (s < 2) { v0 = elu1(v0); v1 = elu1(v1); v2 = elu1(v2); v3 = elu1(v3); }
                    ushort4 o;
                    o.x = f2b(v0); o.y = f2b(v1); o.z = f2b(v2); o.w = f2b(v3);
                    *(ushort4*)&out_u16[(((size_t)s * 64 + bb * 16 + h) * 8192 + n) * 64 + d] = o;
                } else {
                    float4 o; o.x = v0; o.y = v1; o.z = v2; o.w = v3;
                    *(float4*)&out_f32[(size_t)m * Nt + col] = o;
                }
            }
        }
    };

#define PRIO1() __builtin_amdgcn_s_setprio(1)
#define BOUT()  __builtin_amdgcn_s_setprio(0); __builtin_amdgcn_s_barrier()
#define VM6()   asm volatile("s_waitcnt vmcnt(6)" ::: "memory")

    const ushort_t *saC, *sbC, *saN, *sbN;
    int m0, n0, m0N, n0N;
    tilebase(tile_of(0), saC, sbC, m0, n0);
    tilebase(tile_of(nt > 1 ? 1 : 0), saN, sbN, m0N, n0N);

    stageA(saC, 0, 0, 0);
    stageB(sbC, 0, 1, 0);
    stageA(saC, 0, 1, 0);
    stageB(sbC, 0, 0, 0);
    stageA(saC, 1, 0, 64);
    stageB(sbC, 1, 1, 64);
    stageA(saC, 1, 1, 64);
    VM6();
    __builtin_amdgcn_s_barrier();

    for (int ot = 0; ot < nt; ++ot) {
        int ko = 0;
        for (int pr = 0; pr < 7; ++pr, ko += 128) {
            loadA(0, 0); loadB(0, 0);
            stageB(sbC, 1, 0, ko + 64);
            PRIO1(); mma(0, 0); BOUT();

            loadB(0, 1);
            stageA(saC, 0, 0, ko + 128);
            PRIO1(); mma(0, 1); BOUT();

            loadA(0, 1);
            stageB(sbC, 0, 1, ko + 128);
            PRIO1(); mma(1, 1); BOUT();

            loadB(0, 0);
            stageA(saC, 0, 1, ko + 128);
            PRIO1(); mma(1, 0); __builtin_amdgcn_s_setprio(0); VM6();
            __builtin_amdgcn_s_barrier();

            loadA(1, 0); loadB(1, 0);
            stageB(sbC, 0, 0, ko + 128);
            PRIO1(); mma(0, 0); BOUT();

            loadB(1, 1);
            stageA(saC, 1, 0, ko + 192);
            PRIO1(); mma(0, 1); BOUT();

            loadA(1, 1);
            stageB(sbC, 1, 1, ko + 192);
            PRIO1(); mma(1, 1); BOUT();

            loadB(1, 0);
            stageA(saC, 1, 1, ko + 192);
            PRIO1(); mma(1, 0); __builtin_amdgcn_s_setprio(0); VM6();
            __builtin_amdgcn_s_barrier();
        }

        // last iteration: kt14 (buf0), kt15 (buf1); stages next tile's kt0/kt1
        loadA(0, 0); loadB(0, 0);
        stageB(sbC, 1, 0, 960);
        PRIO1(); mma(0, 0); BOUT();

        loadB(0, 1);
        stageA(saN, 0, 0, 0);
        PRIO1(); mma(0, 1); BOUT();

        loadA(0, 1);
        stageB(sbN, 0, 1, 0);
        PRIO1(); mma(1, 1); BOUT();

        loadB(0, 0);
        stageA(saN, 0, 1, 0);
        PRIO1(); mma(1, 0); __builtin_amdgcn_s_setprio(0); VM6();
        __builtin_amdgcn_s_barrier();

        loadA(1, 0); loadB(1, 0);
        stageB(sbN, 0, 0, 0);
        PRIO1(); mma(0, 0); BOUT();

        loadB(1, 1);
        stageA(saN, 1, 0, 64);
        PRIO1(); mma(0, 1); BOUT();

        loadA(1, 1);
        stageB(sbN, 1, 1, 64);
        PRIO1(); mma(1, 1); BOUT();

        loadB(1, 0);
        stageA(saN, 1, 1, 64);
        PRIO1(); mma(1, 0); __builtin_amdgcn_s_setprio(0); VM6();
        __builtin_amdgcn_s_barrier();

        epilogue(m0, n0);
#pragma unroll
        for (int i = 0; i < 8; ++i)
#pragma unroll
            for (int j = 0; j < 4; ++j) acc[i][j] = z4;

        saC = saN; sbC = sbN; m0 = m0N; n0 = n0N;
        const int nxt = (ot + 2 < nt) ? ot + 2 : nt - 1;
        tilebase(tile_of(nxt), saN, sbN, m0N, n0N);
    }

#undef PRIO1
#undef BOUT
#undef VM6
}

// ---------------- kv = k^T v  (+ ksum) per (b,h) ----------------
__global__ __launch_bounds__(256) void kv_kernel(
    const ushort_t* __restrict__ kbuf, const ushort_t* __restrict__ vbuf,
    float* __restrict__ kv, float* __restrict__ ksum)
{
    __shared__ ushort_t ks[64 * 64] __attribute__((aligned(16)));
    __shared__ ushort_t vs[64 * 64] __attribute__((aligned(16)));

    const int bh = blockIdx.y, chunk = blockIdx.x, t = threadIdx.x;
    const int d0 = (t >> 4) * 4, e0 = (t & 15) * 4;
    const bool do_ksum = (t & 15) == 0;

    float acc[4][4];
#pragma unroll
    for (int i = 0; i < 4; ++i)
#pragma unroll
        for (int j = 0; j < 4; ++j) acc[i][j] = 0.f;
    float kacc[4] = {0.f, 0.f, 0.f, 0.f};

    for (int sub = 0; sub < 8; ++sub) {
        const int nb = chunk * 512 + sub * 64;
        __syncthreads();
#pragma unroll
        for (int p = 0; p < 2; ++p) {
            int idx = p * 256 + t;
            int r = idx >> 3, c = (idx & 7) * 8;
            *(short8*)&ks[r * 64 + c] = *(const short8*)&kbuf[((size_t)bh * 8192 + nb + r) * 64 + c];
            *(short8*)&vs[r * 64 + c] = *(const short8*)&vbuf[((size_t)bh * 8192 + nb + r) * 64 + c];
        }
        __syncthreads();
        for (int n = 0; n < 64; ++n) {
            ushort4 kd = *(const ushort4*)&ks[n * 64 + d0];
            ushort4 ve = *(const ushort4*)&vs[n * 64 + e0];
            float kf[4] = {b2f(kd.x), b2f(kd.y), b2f(kd.z), b2f(kd.w)};
            float vf[4] = {b2f(ve.x), b2f(ve.y), b2f(ve.z), b2f(ve.w)};
#pragma unroll
            for (int i = 0; i < 4; ++i) {
#pragma unroll
                for (int j = 0; j < 4; ++j) acc[i][j] += kf[i] * vf[j];
            }
            if (do_ksum) {
#pragma unroll
                for (int i = 0; i < 4; ++i) kacc[i] += kf[i];
            }
        }
    }
#pragma unroll
    for (int i = 0; i < 4; ++i) {
        if (do_ksum) atomicAdd(&ksum[bh * 64 + d0 + i], kacc[i]);
#pragma unroll
        for (int j = 0; j < 4; ++j)
            atomicAdd(&kv[((size_t)bh * 64 + d0 + i) * 64 + e0 + j], acc[i][j]);
    }
}

// ---------------- out = (q @ kv) * z via MFMA, repack to [B][N][C] bf16 ----------------
__global__ __launch_bounds__(256) void out_kernel(
    const ushort_t* __restrict__ qbuf, const float* __restrict__ kv,
    const float* __restrict__ ksum, ushort_t* __restrict__ obuf)
{
    __shared__ float kvs[4096];
    __shared__ float ksums[64];

    const int bh = blockIdx.y, chunk = blockIdx.x, t = threadIdx.x;
    const int b = bh >> 4, h = bh & 15;
    const int wave = t >> 6, lane = t & 63;
    const int tok = lane & 15, fq = lane >> 4;

#pragma unroll
    for (int i = 0; i < 4; ++i) {
        int idx = (i * 256 + t) * 4;
        *(float4*)&kvs[idx] = *(const float4*)&kv[(size_t)bh * 4096 + idx];
    }
    if (t < 64) ksums[t] = ksum[bh * 64 + t];
    __syncthreads();

    short8 afr[4][2];
#pragma unroll
    for (int et = 0; et < 4; ++et)
#pragma unroll
        for (int kslice = 0; kslice < 2; ++kslice)
#pragma unroll
            for (int i = 0; i < 8; ++i) {
                const int d = kslice * 32 + fq * 8 + i;
                afr[et][kslice][i] = (short)f2b(kvs[d * 64 + et * 16 + tok]);
            }
    short8 zfr[2];
#pragma unroll
    for (int kslice = 0; kslice < 2; ++kslice)
#pragma unroll
        for (int i = 0; i < 8; ++i)
            zfr[kslice][i] = (short)f2b(ksums[kslice * 32 + fq * 8 + i]);

    const floatx4 z4 = {0.f, 0.f, 0.f, 0.f};
    const int nbase = chunk * 1024 + wave * 256;
    const ushort_t* qrow = qbuf + ((size_t)bh * 8192 + nbase + tok) * 64 + fq * 8;
    ushort_t* orow = obuf + ((size_t)b * 8192 + nbase + tok) * 1024 + h * 64 + fq * 4;

#pragma unroll 2
    for (int g = 0; g < 16; ++g) {
        short8 bf0 = *(const short8*)(qrow + (size_t)g * 16 * 64);
        short8 bf1 = *(const short8*)(qrow + (size_t)g * 16 * 64 + 32);

        floatx4 az = __builtin_amdgcn_mfma_f32_16x16x32_bf16(zfr[0], bf0, z4, 0, 0, 0);
        az = __builtin_amdgcn_mfma_f32_16x16x32_bf16(zfr[1], bf1, az, 0, 0, 0);

        floatx4 ad[4];
#pragma unroll
        for (int et = 0; et < 4; ++et) {
            ad[et] = __builtin_amdgcn_mfma_f32_16x16x32_bf16(afr[et][0], bf0, z4, 0, 0, 0);
            ad[et] = __builtin_amdgcn_mfma_f32_16x16x32_bf16(afr[et][1], bf1, ad[et], 0, 0, 0);
        }

        const float zi = 1.f / (az[0] + 1e-8f);
#pragma unroll
        for (int et = 0; et < 4; ++et) {
            ushort4 o;
            o.x = f2b(ad[et][0] * zi);
            o.y = f2b(ad[et][1] * zi);
            o.z = f2b(ad[et][2] * zi);
            o.w = f2b(ad[et][3] * zi);
            *(ushort4*)&orow[(size_t)g * 16 * 1024 + et * 16] = o;
        }
    }
}

// ---------------- launch ----------------

extern "C" void kernel_launch(void* const* d_in, const int* in_sizes, int n_in,
                              void* d_out, int out_size, void* d_ws, size_t ws_size,
                              hipStream_t stream) {
    const float* x      = (const float*)d_in[0];
    const float* w_qkv  = (const float*)d_in[1];
    const float* b_qkv  = (const float*)d_in[2];
    const float* w_proj = (const float*)d_in[3];
    const float* b_proj = (const float*)d_in[4];
    float* out = (float*)d_out;

    const size_t XE = (size_t)32768 * 1024;

    char* ws = (char*)d_ws;
    ushort_t* xb   = (ushort_t*)ws;  ws += XE * 2;
    ushort_t* wqT  = (ushort_t*)ws;  ws += (size_t)3072 * 1024 * 2;
    ushort_t* wpT  = (ushort_t*)ws;  ws += (size_t)1024 * 1024 * 2;
    ushort_t* qkvb = (ushort_t*)ws;  ws += 3 * XE * 2;   // [3][64][8192][64] scatter
    ushort_t* ob   = (ushort_t*)ws;  ws += XE * 2;       // [32768][1024]
    float*    kv   = (float*)ws;     ws += (size_t)64 * 64 * 64 * 4;
    float*    ksum = (float*)ws;     ws += (size_t)64 * 64 * 4;

    (void)hipFuncSetAttribute(reinterpret_cast<const void*>(gemm256<0>),
                              hipFuncAttributeMaxDynamicSharedMemorySize, 131072);
    (void)hipFuncSetAttribute(reinterpret_cast<const void*>(gemm256<1>),
                              hipFuncAttributeMaxDynamicSharedMemorySize, 131072);

    // fused prep: wqT (3072 blocks) | wpT (1024) | conv (1024) | zero kv+ksum (128)
    prep_kernel<<<dim3(5248), dim3(256), 0, stream>>>(x, w_qkv, w_proj, xb, wqT, wpT, kv);

    // qkv: 1536 tiles, 256 persistent blocks, nt=6, L2-blocked XCD mapping
    gemm256<0><<<dim3(256), dim3(512), 131072, stream>>>(xb, wqT, b_qkv, qkvb, nullptr, 3072, 6);

    kv_kernel<<<dim3(16, 64), dim3(256), 0, stream>>>(qkvb + XE, qkvb + 2 * XE, kv, ksum);
    out_kernel<<<dim3(8, 64), dim3(256), 0, stream>>>(qkvb, kv, ksum, ob);

    // proj: 512 tiles, 256 persistent blocks, nt=2
    gemm256<1><<<dim3(256), dim3(512), 131072, stream>>>(ob, wpT, b_proj, nullptr, out, 1024, 2);
}

// Round 13
// 466.711 us; speedup vs baseline: 1.1307x; 1.1307x over previous
//
#include <hip/hip_runtime.h>
#include <hip/hip_bf16.h>
#include <stdint.h>

typedef unsigned short ushort_t;
typedef __attribute__((ext_vector_type(8))) short short8;
typedef __attribute__((ext_vector_type(4))) float floatx4;

__device__ __forceinline__ ushort_t f2b(float f) {
    unsigned u = __float_as_uint(f);
    unsigned r = (u + 0x7FFFu + ((u >> 16) & 1u)) >> 16;
    return (ushort_t)r;
}
__device__ __forceinline__ float b2f(ushort_t h) {
    return __uint_as_float(((unsigned)h) << 16);
}
__device__ __forceinline__ float elu1(float f) {
    return (f > 0.f) ? (f + 1.f) : __expf(f);
}

#define GLDS16(srcp, dstp)                                                          \
    __builtin_amdgcn_global_load_lds(                                               \
        (const __attribute__((address_space(1))) unsigned int*)(srcp),              \
        (__attribute__((address_space(3))) unsigned int*)(dstp), 16, 0, 0)

// ---------------- conversion kernels ----------------

__global__ void conv_bf16(const float* __restrict__ in, ushort_t* __restrict__ out, int n8) {
    for (int i = blockIdx.x * blockDim.x + threadIdx.x; i < n8; i += gridDim.x * blockDim.x) {
        const float4 f0 = *(const float4*)&in[(size_t)i * 8];
        const float4 f1 = *(const float4*)&in[(size_t)i * 8 + 4];
        ushort4 o0, o1;
        o0.x = f2b(f0.x); o0.y = f2b(f0.y); o0.z = f2b(f0.z); o0.w = f2b(f0.w);
        o1.x = f2b(f1.x); o1.y = f2b(f1.y); o1.z = f2b(f1.z); o1.w = f2b(f1.w);
        *(ushort4*)&out[(size_t)i * 8]     = o0;
        *(ushort4*)&out[(size_t)i * 8 + 4] = o1;
    }
}

__global__ void transpose_conv(const float* __restrict__ in, ushort_t* __restrict__ out,
                               int R, int C) {
    __shared__ float tile[32][33];
    int c0 = blockIdx.x * 32, r0 = blockIdx.y * 32;
    int tx = threadIdx.x, ty = threadIdx.y;
#pragma unroll
    for (int k = 0; k < 4; ++k) {
        int a = ty * 4 + k;
        tile[a][tx] = in[(size_t)(r0 + a) * C + c0 + tx];
    }
    __syncthreads();
#pragma unroll
    for (int k = 0; k < 4; ++k) {
        int a = ty * 4 + k;
        out[(size_t)(c0 + a) * R + r0 + tx] = f2b(tile[tx][a]);
    }
}

__global__ void zero_f32(float* __restrict__ p, int n) {
    int i = blockIdx.x * blockDim.x + threadIdx.x;
    if (i < n) p[i] = 0.f;
}

// ---------------- persistent 256x256 8-phase GEMM (16x16x32): C = A @ Bt^T, K=1024 ----------------
// (identical to round 8)
template<int MODE>
__global__ __launch_bounds__(512, 2) void gemm256(
    const ushort_t* __restrict__ A, const ushort_t* __restrict__ Bt,
    const float* __restrict__ bias,
    ushort_t* __restrict__ out_u16, float* __restrict__ out_f32,
    int Nt, int nbx, int nt)
{
    extern __shared__ ushort_t lds[];   // 65536 elements = 128 KiB
    constexpr int KK = 1024;

    const int tid  = threadIdx.x;
    const int wave = tid >> 6;
    const int lane = tid & 63;
    const int wm_i = wave >> 2;
    const int wn_i = wave & 3;
    const int fr   = lane & 15;
    const int fq   = lane >> 4;

    const int bid  = (int)blockIdx.x;
    const int bswz = ((bid & 7) << 5) + (bid >> 3);
    const int ntiles = nt << 8;

    const int trow = tid >> 3;
    const int csw  = ((tid & 7) ^ (trow & 7)) << 3;
    const int tcolB = ((tid >> 8) << 6) + (trow & 31);

    const int dstA = wave * 512;
    const int dstB = 16384 + wave * 512;

    const int sw0 = (fq ^ (fr & 7)) << 3;
    const int sw1 = sw0 ^ 32;
    const int abase = (wm_i * 64 + fr) * 64;
    const int bbase = (wn_i * 32 + fr) * 64;
    int loA0[2][2], loA1[2][2], loB0[2][2], loB1[2][2];
#pragma unroll
    for (int bf = 0; bf < 2; ++bf)
#pragma unroll
        for (int q = 0; q < 2; ++q) {
            loA0[bf][q] = bf * 32768 + q * 8192 + abase + sw0;
            loA1[bf][q] = bf * 32768 + q * 8192 + abase + sw1;
            loB0[bf][q] = bf * 32768 + 16384 + q * 8192 + bbase + sw0;
            loB1[bf][q] = bf * 32768 + 16384 + q * 8192 + bbase + sw1;
        }

    floatx4 acc[8][4];
    const floatx4 z4 = {0.f, 0.f, 0.f, 0.f};
#pragma unroll
    for (int i = 0; i < 8; ++i)
#pragma unroll
        for (int j = 0; j < 4; ++j) acc[i][j] = z4;

    short8 a[4][2], b[2][2];

    auto tilebase = [&](int t, const ushort_t*& sA, const ushort_t*& sB, int& mm, int& nn) {
        const int byy = t / nbx;
        const int bxx = t - byy * nbx;
        mm = byy << 8; nn = bxx << 8;
        sA = A  + (size_t)(mm + trow)  * KK + csw;
        sB = Bt + (size_t)(nn + tcolB) * KK + csw;
    };

    auto stageA = [&](const ushort_t* sp, int buf, int h, int ko) {
        ushort_t* d = lds + buf * 32768 + h * 8192 + dstA;
        GLDS16(sp + h * (64 * KK) + ko, d);
        GLDS16(sp + h * (64 * KK) + 128 * KK + ko, d + 4096);
    };
    auto stageB = [&](const ushort_t* sp, int buf, int h, int ko) {
        ushort_t* d = lds + buf * 32768 + h * 8192 + dstB;
        GLDS16(sp + h * (32 * KK) + ko, d);
        GLDS16(sp + h * (32 * KK) + 128 * KK + ko, d + 4096);
    };
    auto loadA = [&](int buf, int qr) {
        const int o0 = loA0[buf][qr], o1 = loA1[buf][qr];
#pragma unroll
        for (int i = 0; i < 4; ++i) {
            a[i][0] = *(const short8*)(lds + o0 + i * 1024);
            a[i][1] = *(const short8*)(lds + o1 + i * 1024);
        }
    };
    auto loadB = [&](int buf, int qc) {
        const int o0 = loB0[buf][qc], o1 = loB1[buf][qc];
#pragma unroll
        for (int j = 0; j < 2; ++j) {
            b[j][0] = *(const short8*)(lds + o0 + j * 1024);
            b[j][1] = *(const short8*)(lds + o1 + j * 1024);
        }
    };
    // swapped operands: D^T -> lane fq*4+r indexes n (cols), fr indexes m (rows)
    auto mma = [&](int qr, int qc) {
#pragma unroll
        for (int i = 0; i < 4; ++i)
#pragma unroll
            for (int j = 0; j < 2; ++j) {
                acc[qr * 4 + i][qc * 2 + j] =
                    __builtin_amdgcn_mfma_f32_16x16x32_bf16(b[j][0], a[i][0], acc[qr * 4 + i][qc * 2 + j], 0, 0, 0);
                acc[qr * 4 + i][qc * 2 + j] =
                    __builtin_amdgcn_mfma_f32_16x16x32_bf16(b[j][1], a[i][1], acc[qr * 4 + i][qc * 2 + j], 0, 0, 0);
            }
    };

    auto epilogue = [&](int m0, int n0) {
        float4 bv[4];
#pragma unroll
        for (int cj = 0; cj < 4; ++cj) {
            const int nb = n0 + wn_i * 64 + (cj >> 1) * 32 + (cj & 1) * 16 + fq * 4;
            bv[cj] = *(const float4*)&bias[nb];
        }
#pragma unroll
        for (int ri = 0; ri < 8; ++ri) {
            const int m = m0 + wm_i * 128 + (ri >> 2) * 64 + (ri & 3) * 16 + fr;
#pragma unroll
            for (int cj = 0; cj < 4; ++cj) {
                const int col = n0 + wn_i * 64 + (cj >> 1) * 32 + (cj & 1) * 16 + fq * 4;
                float v0 = acc[ri][cj][0] + bv[cj].x;
                float v1 = acc[ri][cj][1] + bv[cj].y;
                float v2 = acc[ri][cj][2] + bv[cj].z;
                float v3 = acc[ri][cj][3] + bv[cj].w;
                if (MODE == 0) {
                    const int s  = col >> 10;
                    const int c  = col & 1023;
                    const int h  = c >> 6;
                    const int d  = c & 63;
                    const int bb = m >> 13;
                    const int n  = m & 8191;
                    if (s < 2) { v0 = elu1(v0); v1 = elu1(v1); v2 = elu1(v2); v3 = elu1(v3); }
                    ushort4 o;
                    o.x = f2b(v0); o.y = f2b(v1); o.z = f2b(v2); o.w = f2b(v3);
                    *(ushort4*)&out_u16[(((size_t)s * 64 + bb * 16 + h) * 8192 + n) * 64 + d] = o;
                } else {
                    float4 o; o.x = v0; o.y = v1; o.z = v2; o.w = v3;
                    *(float4*)&out_f32[(size_t)m * Nt + col] = o;
                }
            }
        }
    };

#define PRIO1() __builtin_amdgcn_s_setprio(1)
#define BOUT()  __builtin_amdgcn_s_setprio(0); __builtin_amdgcn_s_barrier()
#define VM6()   asm volatile("s_waitcnt vmcnt(6)" ::: "memory")

    const ushort_t *saC, *sbC, *saN, *sbN;
    int m0, n0, m0N, n0N;
    int tC = bswz;
    tilebase(tC, saC, sbC, m0, n0);
    int tN = (tC + 256 < ntiles) ? tC + 256 : tC;
    tilebase(tN, saN, sbN, m0N, n0N);

    stageA(saC, 0, 0, 0);
    stageB(sbC, 0, 1, 0);
    stageA(saC, 0, 1, 0);
    stageB(sbC, 0, 0, 0);
    stageA(saC, 1, 0, 64);
    stageB(sbC, 1, 1, 64);
    stageA(saC, 1, 1, 64);
    VM6();
    __builtin_amdgcn_s_barrier();

    for (int ot = 0; ot < nt; ++ot) {
        int ko = 0;
        for (int pr = 0; pr < 7; ++pr, ko += 128) {
            loadA(0, 0); loadB(0, 0);
            stageB(sbC, 1, 0, ko + 64);
            PRIO1(); mma(0, 0); BOUT();

            loadB(0, 1);
            stageA(saC, 0, 0, ko + 128);
            PRIO1(); mma(0, 1); BOUT();

            loadA(0, 1);
            stageB(sbC, 0, 1, ko + 128);
            PRIO1(); mma(1, 1); BOUT();

            loadB(0, 0);
            stageA(saC, 0, 1, ko + 128);
            PRIO1(); mma(1, 0); __builtin_amdgcn_s_setprio(0); VM6();
            __builtin_amdgcn_s_barrier();

            loadA(1, 0); loadB(1, 0);
            stageB(sbC, 0, 0, ko + 128);
            PRIO1(); mma(0, 0); BOUT();

            loadB(1, 1);
            stageA(saC, 1, 0, ko + 192);
            PRIO1(); mma(0, 1); BOUT();

            loadA(1, 1);
            stageB(sbC, 1, 1, ko + 192);
            PRIO1(); mma(1, 1); BOUT();

            loadB(1, 0);
            stageA(saC, 1, 1, ko + 192);
            PRIO1(); mma(1, 0); __builtin_amdgcn_s_setprio(0); VM6();
            __builtin_amdgcn_s_barrier();
        }

        loadA(0, 0); loadB(0, 0);
        stageB(sbC, 1, 0, 960);
        PRIO1(); mma(0, 0); BOUT();

        loadB(0, 1);
        stageA(saN, 0, 0, 0);
        PRIO1(); mma(0, 1); BOUT();

        loadA(0, 1);
        stageB(sbN, 0, 1, 0);
        PRIO1(); mma(1, 1); BOUT();

        loadB(0, 0);
        stageA(saN, 0, 1, 0);
        PRIO1(); mma(1, 0); __builtin_amdgcn_s_setprio(0); VM6();
        __builtin_amdgcn_s_barrier();

        loadA(1, 0); loadB(1, 0);
        stageB(sbN, 0, 0, 0);
        PRIO1(); mma(0, 0); BOUT();

        loadB(1, 1);
        stageA(saN, 1, 0, 64);
        PRIO1(); mma(0, 1); BOUT();

        loadA(1, 1);
        stageB(sbN, 1, 1, 64);
        PRIO1(); mma(1, 1); BOUT();

        loadB(1, 0);
        stageA(saN, 1, 1, 64);
        PRIO1(); mma(1, 0); __builtin_amdgcn_s_setprio(0); VM6();
        __builtin_amdgcn_s_barrier();

        epilogue(m0, n0);
#pragma unroll
        for (int i = 0; i < 8; ++i)
#pragma unroll
            for (int j = 0; j < 4; ++j) acc[i][j] = z4;

        saC = saN; sbC = sbN; m0 = m0N; n0 = n0N; tC = tN;
        tN = (tC + 256 < ntiles) ? tC + 256 : tC;
        tilebase(tN, saN, sbN, m0N, n0N);
    }

#undef PRIO1
#undef BOUT
#undef VM6
}

// ---------------- kv = k^T v  (+ ksum) per (b,h) — double-buffered ----------------
__global__ __launch_bounds__(256) void kv_kernel(
    const ushort_t* __restrict__ kbuf, const ushort_t* __restrict__ vbuf,
    float* __restrict__ kv, float* __restrict__ ksum)
{
    __shared__ ushort_t ks[2][64 * 64] __attribute__((aligned(16)));
    __shared__ ushort_t vs[2][64 * 64] __attribute__((aligned(16)));

    const int bh = blockIdx.y, chunk = blockIdx.x, t = threadIdx.x;
    const int d0 = (t >> 4) * 4, e0 = (t & 15) * 4;
    const bool do_ksum = (t & 15) == 0;

    // staging addresses (two short8 per array per sub)
    const int r0s = t >> 3, c0s = (t & 7) * 8;            // idx = t
    const int r1s = (256 + t) >> 3, c1s = c0s;            // idx = 256 + t

    float acc[4][4];
#pragma unroll
    for (int i = 0; i < 4; ++i)
#pragma unroll
        for (int j = 0; j < 4; ++j) acc[i][j] = 0.f;
    float kacc[4] = {0.f, 0.f, 0.f, 0.f};

    short8 krg[2], vrg[2];
    auto gload = [&](int sub, short8* kr, short8* vr) {
        const size_t nb = (size_t)bh * 8192 + chunk * 512 + sub * 64;
        kr[0] = *(const short8*)&kbuf[(nb + r0s) * 64 + c0s];
        kr[1] = *(const short8*)&kbuf[(nb + r1s) * 64 + c1s];
        vr[0] = *(const short8*)&vbuf[(nb + r0s) * 64 + c0s];
        vr[1] = *(const short8*)&vbuf[(nb + r1s) * 64 + c1s];
    };
    auto swrite = [&](int buf, const short8* kr, const short8* vr) {
        *(short8*)&ks[buf][r0s * 64 + c0s] = kr[0];
        *(short8*)&ks[buf][r1s * 64 + c1s] = kr[1];
        *(short8*)&vs[buf][r0s * 64 + c0s] = vr[0];
        *(short8*)&vs[buf][r1s * 64 + c1s] = vr[1];
    };

    gload(0, krg, vrg);
    swrite(0, krg, vrg);
    __syncthreads();

    for (int sub = 0; sub < 8; ++sub) {
        const int cur = sub & 1;
        if (sub < 7) gload(sub + 1, krg, vrg);   // in flight during compute

        for (int n = 0; n < 64; ++n) {
            ushort4 kd = *(const ushort4*)&ks[cur][n * 64 + d0];
            ushort4 ve = *(const ushort4*)&vs[cur][n * 64 + e0];
            float kf[4] = {b2f(kd.x), b2f(kd.y), b2f(kd.z), b2f(kd.w)};
            float vf[4] = {b2f(ve.x), b2f(ve.y), b2f(ve.z), b2f(ve.w)};
#pragma unroll
            for (int i = 0; i < 4; ++i) {
#pragma unroll
                for (int j = 0; j < 4; ++j) acc[i][j] += kf[i] * vf[j];
            }
            if (do_ksum) {
#pragma unroll
                for (int i = 0; i < 4; ++i) kacc[i] += kf[i];
            }
        }

        if (sub < 7) {
            swrite(cur ^ 1, krg, vrg);   // safe: buf cur^1 last read before prev barrier
            __syncthreads();
        }
    }

#pragma unroll
    for (int i = 0; i < 4; ++i) {
        if (do_ksum) atomicAdd(&ksum[bh * 64 + d0 + i], kacc[i]);
#pragma unroll
        for (int j = 0; j < 4; ++j)
            atomicAdd(&kv[((size_t)bh * 64 + d0 + i) * 64 + e0 + j], acc[i][j]);
    }
}

// ---------------- out = (q @ kv) * z via MFMA, repack to [B][N][C] bf16 ----------------
__global__ __launch_bounds__(256) void out_kernel(
    const ushort_t* __restrict__ qbuf, const float* __restrict__ kv,
    const float* __restrict__ ksum, ushort_t* __restrict__ obuf)
{
    __shared__ float kvs[4096];
    __shared__ float ksums[64];

    const int bh = blockIdx.y, chunk = blockIdx.x, t = threadIdx.x;
    const int b = bh >> 4, h = bh & 15;
    const int wave = t >> 6, lane = t & 63;
    const int tok = lane & 15, fq = lane >> 4;

#pragma unroll
    for (int i = 0; i < 4; ++i) {
        int idx = (i * 256 + t) * 4;
        *(float4*)&kvs[idx] = *(const float4*)&kv[(size_t)bh * 4096 + idx];
    }
    if (t < 64) ksums[t] = ksum[bh * 64 + t];
    __syncthreads();

    short8 afr[4][2];
#pragma unroll
    for (int et = 0; et < 4; ++et)
#pragma unroll
        for (int kslice = 0; kslice < 2; ++kslice)
#pragma unroll
            for (int i = 0; i < 8; ++i) {
                const int d = kslice * 32 + fq * 8 + i;
                afr[et][kslice][i] = (short)f2b(kvs[d * 64 + et * 16 + tok]);
            }
    short8 zfr[2];
#pragma unroll
    for (int kslice = 0; kslice < 2; ++kslice)
#pragma unroll
        for (int i = 0; i < 8; ++i)
            zfr[kslice][i] = (short)f2b(ksums[kslice * 32 + fq * 8 + i]);

    const floatx4 z4 = {0.f, 0.f, 0.f, 0.f};
    const int nbase = chunk * 1024 + wave * 256;
    const ushort_t* qrow = qbuf + ((size_t)bh * 8192 + nbase + tok) * 64 + fq * 8;
    ushort_t* orow = obuf + ((size_t)b * 8192 + nbase + tok) * 1024 + h * 64 + fq * 4;

#pragma unroll 2
    for (int g = 0; g < 16; ++g) {
        short8 bf0 = *(const short8*)(qrow + (size_t)g * 16 * 64);
        short8 bf1 = *(const short8*)(qrow + (size_t)g * 16 * 64 + 32);

        floatx4 az = __builtin_amdgcn_mfma_f32_16x16x32_bf16(zfr[0], bf0, z4, 0, 0, 0);
        az = __builtin_amdgcn_mfma_f32_16x16x32_bf16(zfr[1], bf1, az, 0, 0, 0);

        floatx4 ad[4];
#pragma unroll
        for (int et = 0; et < 4; ++et) {
            ad[et] = __builtin_amdgcn_mfma_f32_16x16x32_bf16(afr[et][0], bf0, z4, 0, 0, 0);
            ad[et] = __builtin_amdgcn_mfma_f32_16x16x32_bf16(afr[et][1], bf1, ad[et], 0, 0, 0);
        }

        const float zi = 1.f / (az[0] + 1e-8f);
#pragma unroll
        for (int et = 0; et < 4; ++et) {
            ushort4 o;
            o.x = f2b(ad[et][0] * zi);
            o.y = f2b(ad[et][1] * zi);
            o.z = f2b(ad[et][2] * zi);
            o.w = f2b(ad[et][3] * zi);
            *(ushort4*)&orow[(size_t)g * 16 * 1024 + et * 16] = o;
        }
    }
}

// ---------------- launch ----------------

extern "C" void kernel_launch(void* const* d_in, const int* in_sizes, int n_in,
                              void* d_out, int out_size, void* d_ws, size_t ws_size,
                              hipStream_t stream) {
    const float* x      = (const float*)d_in[0];
    const float* w_qkv  = (const float*)d_in[1];
    const float* b_qkv  = (const float*)d_in[2];
    const float* w_proj = (const float*)d_in[3];
    const float* b_proj = (const float*)d_in[4];
    float* out = (float*)d_out;

    const size_t XE = (size_t)32768 * 1024;

    char* ws = (char*)d_ws;
    ushort_t* xb   = (ushort_t*)ws;  ws += XE * 2;
    ushort_t* wqT  = (ushort_t*)ws;  ws += (size_t)3072 * 1024 * 2;
    ushort_t* wpT  = (ushort_t*)ws;  ws += (size_t)1024 * 1024 * 2;
    ushort_t* qkvb = (ushort_t*)ws;  ws += 3 * XE * 2;   // [3][64][8192][64] scatter
    ushort_t* ob   = (ushort_t*)ws;  ws += XE * 2;       // [32768][1024]
    float*    kv   = (float*)ws;     ws += (size_t)64 * 64 * 64 * 4;
    float*    ksum = (float*)ws;     ws += (size_t)64 * 64 * 4;

    (void)hipFuncSetAttribute(reinterpret_cast<const void*>(gemm256<0>),
                              hipFuncAttributeMaxDynamicSharedMemorySize, 131072);
    (void)hipFuncSetAttribute(reinterpret_cast<const void*>(gemm256<1>),
                              hipFuncAttributeMaxDynamicSharedMemorySize, 131072);

    zero_f32<<<dim3((64 * 64 * 64 + 64 * 64 + 255) / 256), dim3(256), 0, stream>>>(kv, 64 * 64 * 64 + 64 * 64);
    conv_bf16<<<dim3(2048), dim3(256), 0, stream>>>(x, xb, (int)(XE / 8));
    transpose_conv<<<dim3(96, 32), dim3(32, 8), 0, stream>>>(w_qkv, wqT, 1024, 3072);
    transpose_conv<<<dim3(32, 32), dim3(32, 8), 0, stream>>>(w_proj, wpT, 1024, 1024);

    // qkv: 1536 tiles, 256 persistent blocks, nt=6
    gemm256<0><<<dim3(256), dim3(512), 131072, stream>>>(xb, wqT, b_qkv, qkvb, nullptr, 3072, 12, 6);

    kv_kernel<<<dim3(16, 64), dim3(256), 0, stream>>>(qkvb + XE, qkvb + 2 * XE, kv, ksum);
    out_kernel<<<dim3(8, 64), dim3(256), 0, stream>>>(qkvb, kv, ksum, ob);

    // proj: 512 tiles, 256 persistent blocks, nt=2
    gemm256<1><<<dim3(256), dim3(512), 131072, stream>>>(ob, wpT, b_proj, nullptr, out, 1024, 4, 2);
}